// Round 1
// baseline (2641.368 us; speedup 1.0000x reference)
//
#include <hip/hip_runtime.h>

// ---------------------------------------------------------------------------
// UMLSGraphEmbedding: 2-filter x 2-layer hetero GraphSAGE, D=128, f32.
// Round 0: correct-first. CSR-based mean aggregation + fused f32 GEMM.
// ---------------------------------------------------------------------------

constexpr int D_ = 128;
constexpr int SCAN_BLOCK = 256;
constexpr int SCAN_ITEMS = 8;
constexpr int SCAN_CHUNK = SCAN_BLOCK * SCAN_ITEMS; // 2048

// ---------------- CSR build ----------------

__global__ void csr_count(const int* __restrict__ dst, int* __restrict__ cnt, int E) {
    int e = blockIdx.x * 256 + threadIdx.x;
    if (e < E) atomicAdd(&cnt[dst[e]], 1);
}

__global__ void scan_partial(const int* __restrict__ cnt, int* __restrict__ rowptr,
                             int* __restrict__ blockSums, int n) {
    __shared__ int s[SCAN_BLOCK];
    int base = blockIdx.x * SCAN_CHUNK + threadIdx.x * SCAN_ITEMS;
    int v[SCAN_ITEMS];
    int sum = 0;
    #pragma unroll
    for (int i = 0; i < SCAN_ITEMS; ++i) {
        int idx = base + i;
        v[i] = (idx < n) ? cnt[idx] : 0;
        sum += v[i];
    }
    s[threadIdx.x] = sum;
    __syncthreads();
    for (int off = 1; off < SCAN_BLOCK; off <<= 1) {
        int t = (threadIdx.x >= off) ? s[threadIdx.x - off] : 0;
        __syncthreads();
        s[threadIdx.x] += t;
        __syncthreads();
    }
    int excl = s[threadIdx.x] - sum;   // exclusive prefix of this thread within block
    int run = excl;
    #pragma unroll
    for (int i = 0; i < SCAN_ITEMS; ++i) {
        int idx = base + i;
        run += v[i];
        if (idx < n) rowptr[idx + 1] = run;  // inclusive within block, pre-offset
    }
    if (threadIdx.x == 0) blockSums[blockIdx.x] = s[SCAN_BLOCK - 1];
}

__global__ void scan_blocksums(int* blockSums, int nb) {
    __shared__ int s[SCAN_BLOCK];
    int v = (threadIdx.x < nb) ? blockSums[threadIdx.x] : 0;
    s[threadIdx.x] = v;
    __syncthreads();
    for (int off = 1; off < SCAN_BLOCK; off <<= 1) {
        int t = (threadIdx.x >= off) ? s[threadIdx.x - off] : 0;
        __syncthreads();
        s[threadIdx.x] += t;
        __syncthreads();
    }
    if (threadIdx.x < nb) blockSums[threadIdx.x] = s[threadIdx.x] - v; // exclusive
}

__global__ void scan_add(int* __restrict__ rowptr, const int* __restrict__ blockSums, int n) {
    int idx = blockIdx.x * blockDim.x + threadIdx.x;
    if (idx < n) rowptr[idx + 1] += blockSums[idx / SCAN_CHUNK];
    if (idx == 0) rowptr[0] = 0;
}

__global__ void csr_fill(const int* __restrict__ src, const int* __restrict__ dst,
                         const int* __restrict__ rowptr, int* __restrict__ fill,
                         int* __restrict__ col, int E) {
    int e = blockIdx.x * 256 + threadIdx.x;
    if (e >= E) return;
    int d = dst[e];
    int pos = rowptr[d] + atomicAdd(&fill[d], 1);
    col[pos] = src[e];
}

// ---------------- mean aggregation: one wave per destination row ----------------

__global__ __launch_bounds__(256)
void agg_mean(const float* __restrict__ hsrc, const int* __restrict__ rowptr,
              const int* __restrict__ col, float* __restrict__ agg, int n) {
    int row = blockIdx.x * 4 + (threadIdx.x >> 6);
    if (row >= n) return;
    int lane = threadIdx.x & 63;
    int beg = rowptr[row], end = rowptr[row + 1];
    float ax = 0.f, ay = 0.f;
    int e = beg;
    for (; e + 2 <= end; e += 2) {
        int j0 = col[e], j1 = col[e + 1];
        float2 v0 = *(const float2*)(hsrc + (size_t)j0 * D_ + lane * 2);
        float2 v1 = *(const float2*)(hsrc + (size_t)j1 * D_ + lane * 2);
        ax += v0.x + v1.x;
        ay += v0.y + v1.y;
    }
    if (e < end) {
        int j = col[e];
        float2 v = *(const float2*)(hsrc + (size_t)j * D_ + lane * 2);
        ax += v.x;
        ay += v.y;
    }
    float inv = 1.f / fmaxf((float)(end - beg), 1.f);
    *(float2*)(agg + (size_t)row * D_ + lane * 2) = make_float2(ax * inv, ay * inv);
}

// ---------------- small helper: Wsum = A + B (128x128) ----------------

__global__ void wadd(const float* __restrict__ a, const float* __restrict__ b,
                     float* __restrict__ o) {
    int i = blockIdx.x * 256 + threadIdx.x;
    if (i < D_ * D_) o[i] = a[i] + b[i];
}

// ---------------- fused GEMM: Y = epi( bias + sum_m Xm @ Wm^T ) ----------------
// Block: 256 threads, tile 32 rows x 128 cols, thread computes 4x4.
// LDS: Ws transposed (64KB) + Xs (16KB) = 80KB -> 2 blocks/CU.
// mode: 0 = write, 1 = relu+write, 3 = max(existing, res)+write.

template <int M>
__global__ __launch_bounds__(256, 2)
void gemm_fused(const float* __restrict__ X0, const float* __restrict__ W0,
                const float* __restrict__ X1, const float* __restrict__ W1,
                const float* __restrict__ X2, const float* __restrict__ W2,
                const float* __restrict__ b0, const float* __restrict__ b1,
                float* __restrict__ Y, int n, int mode) {
    __shared__ float Ws[D_ * D_];     // Ws[k*128 + j] = W[j*128 + k]
    __shared__ float Xs[32 * D_];     // Xs[r*128 + k]
    const int tid = threadIdx.x;
    const int c0 = (tid & 31) << 2;   // 4 consecutive output cols
    const int r0 = (tid >> 5) << 2;   // 4 consecutive rows within the 32-row tile
    const int row0 = blockIdx.x << 5;

    float acc[4][4];
    float bias[4] = {0.f, 0.f, 0.f, 0.f};
    if (b0) {
        bias[0] = b0[c0 + 0]; bias[1] = b0[c0 + 1];
        bias[2] = b0[c0 + 2]; bias[3] = b0[c0 + 3];
    }
    if (b1) {
        bias[0] += b1[c0 + 0]; bias[1] += b1[c0 + 1];
        bias[2] += b1[c0 + 2]; bias[3] += b1[c0 + 3];
    }
    #pragma unroll
    for (int ri = 0; ri < 4; ++ri)
        #pragma unroll
        for (int ci = 0; ci < 4; ++ci) acc[ri][ci] = bias[ci];

    const float* Xarr[3] = {X0, X1, X2};
    const float* Warr[3] = {W0, W1, W2};

    #pragma unroll
    for (int m = 0; m < M; ++m) {
        const float* __restrict__ W = Warr[m];
        const float* __restrict__ X = Xarr[m];
        __syncthreads();  // protect previous iteration's LDS reads
        // stage W transposed: lanes take consecutive j (conflict-free LDS writes)
        #pragma unroll
        for (int it = 0; it < 16; ++it) {
            int q = tid + it * 256;
            int j = q & 127;
            int k4 = (q >> 7) << 2;
            float4 w = *(const float4*)(W + j * D_ + k4);
            Ws[(k4 + 0) * D_ + j] = w.x;
            Ws[(k4 + 1) * D_ + j] = w.y;
            Ws[(k4 + 2) * D_ + j] = w.z;
            Ws[(k4 + 3) * D_ + j] = w.w;
        }
        // stage X tile (row-major, float4 coalesced)
        #pragma unroll
        for (int it = 0; it < 4; ++it) {
            int q = tid + it * 256;
            int r = q >> 5;
            int k4 = (q & 31) << 2;
            float4 x;
            if (row0 + r < n)
                x = *(const float4*)(X + (size_t)(row0 + r) * D_ + k4);
            else
                x = make_float4(0.f, 0.f, 0.f, 0.f);
            *(float4*)(Xs + r * D_ + k4) = x;
        }
        __syncthreads();
        #pragma unroll 4
        for (int k = 0; k < D_; ++k) {
            float4 w = *(const float4*)(Ws + k * D_ + c0);
            float x0 = Xs[(r0 + 0) * D_ + k];
            float x1 = Xs[(r0 + 1) * D_ + k];
            float x2 = Xs[(r0 + 2) * D_ + k];
            float x3 = Xs[(r0 + 3) * D_ + k];
            acc[0][0] += x0 * w.x; acc[0][1] += x0 * w.y; acc[0][2] += x0 * w.z; acc[0][3] += x0 * w.w;
            acc[1][0] += x1 * w.x; acc[1][1] += x1 * w.y; acc[1][2] += x1 * w.z; acc[1][3] += x1 * w.w;
            acc[2][0] += x2 * w.x; acc[2][1] += x2 * w.y; acc[2][2] += x2 * w.z; acc[2][3] += x2 * w.w;
            acc[3][0] += x3 * w.x; acc[3][1] += x3 * w.y; acc[3][2] += x3 * w.z; acc[3][3] += x3 * w.w;
        }
    }

    #pragma unroll
    for (int ri = 0; ri < 4; ++ri) {
        int row = row0 + r0 + ri;
        if (row >= n) continue;
        float4 res = make_float4(acc[ri][0], acc[ri][1], acc[ri][2], acc[ri][3]);
        float* y = Y + (size_t)row * D_ + c0;
        if (mode == 1) {
            res.x = fmaxf(res.x, 0.f); res.y = fmaxf(res.y, 0.f);
            res.z = fmaxf(res.z, 0.f); res.w = fmaxf(res.w, 0.f);
        } else if (mode == 3) {
            float4 o = *(const float4*)y;
            res.x = fmaxf(res.x, o.x); res.y = fmaxf(res.y, o.y);
            res.z = fmaxf(res.z, o.z); res.w = fmaxf(res.w, o.w);
        }
        *(float4*)y = res;
    }
}

// ---------------------------------------------------------------------------

extern "C" void kernel_launch(void* const* d_in, const int* in_sizes, int n_in,
                              void* d_out, int out_size, void* d_ws, size_t ws_size,
                              hipStream_t stream) {
    const float* x_cui = (const float*)d_in[0];
    const float* x_vis = (const float*)d_in[1];
    const float* W_l   = (const float*)d_in[2];
    const float* b_l   = (const float*)d_in[3];
    const float* W_r   = (const float*)d_in[4];
    const int*   ei_cc = (const int*)d_in[5];
    const int*   ei_vc = (const int*)d_in[6];
    const int*   ei_cv = (const int*)d_in[7];

    const int NC  = in_sizes[0] / D_;   // 100000
    const int NV  = in_sizes[1] / D_;   // 50000
    const int ECC = in_sizes[5] / 2;    // 1600000
    const int EVC = in_sizes[6] / 2;    // 1000000
    const int ECV = in_sizes[7] / 2;    // 1000000
    const int NF = 2, NL = 2;

    // ---- workspace bump allocator ----
    char* ws = (char*)d_ws;
    size_t off = 0;
    auto alloc = [&](size_t bytes) -> char* {
        char* p = ws + off;
        off += (bytes + 511) & ~(size_t)511;
        return p;
    };
    int* rp_cc   = (int*)alloc((size_t)(NC + 1) * 4);
    int* rp_vc   = (int*)alloc((size_t)(NC + 1) * 4);
    int* rp_cv   = (int*)alloc((size_t)(NV + 1) * 4);
    int* col_cc  = (int*)alloc((size_t)ECC * 4);
    int* col_vc  = (int*)alloc((size_t)EVC * 4);
    int* col_cv  = (int*)alloc((size_t)ECV * 4);
    int* cnt     = (int*)alloc((size_t)(NC + 1) * 4);  // reused count/fill temp
    int* bsums   = (int*)alloc(1024);
    float* wsum  = (float*)alloc((size_t)D_ * D_ * 4);
    float* hA_cui = (float*)alloc((size_t)NC * D_ * 4);
    float* hA_vis = (float*)alloc((size_t)NV * D_ * 4);
    float* agg_a  = (float*)alloc((size_t)NC * D_ * 4);
    float* agg_b  = (float*)alloc((size_t)NC * D_ * 4);
    (void)ws_size;

    // ---- build CSR for the 3 edge types (edges are layer/filter invariant) ----
    auto build_csr = [&](const int* ei, int E, int n_dst, int* rowptr, int* colbuf) {
        const int* src = ei;
        const int* dst = ei + E;
        hipMemsetAsync(cnt, 0, (size_t)n_dst * 4, stream);
        csr_count<<<(E + 255) / 256, 256, 0, stream>>>(dst, cnt, E);
        int nb = (n_dst + SCAN_CHUNK - 1) / SCAN_CHUNK;
        scan_partial<<<nb, SCAN_BLOCK, 0, stream>>>(cnt, rowptr, bsums, n_dst);
        scan_blocksums<<<1, SCAN_BLOCK, 0, stream>>>(bsums, nb);
        scan_add<<<(n_dst + 255) / 256, 256, 0, stream>>>(rowptr, bsums, n_dst);
        hipMemsetAsync(cnt, 0, (size_t)n_dst * 4, stream);
        csr_fill<<<(E + 255) / 256, 256, 0, stream>>>(src, dst, rowptr, cnt, colbuf, E);
    };
    build_csr(ei_cc, ECC, NC, rp_cc, col_cc);
    build_csr(ei_vc, EVC, NC, rp_vc, col_vc);
    build_csr(ei_cv, ECV, NV, rp_cv, col_cv);

    float* out_cui = (float*)d_out;
    float* out_vis = (float*)d_out + (size_t)NC * D_;

    // ---- 2 filters x 2 layers ----
    for (int f = 0; f < NF; ++f) {
        const float* hc = x_cui;
        const float* hv = x_vis;
        for (int l = 0; l < NL; ++l) {
            size_t base = ((size_t)f * NL + l) * 3;
            const float* Wl0 = W_l + (base + 0) * D_ * D_;
            const float* Wl1 = W_l + (base + 1) * D_ * D_;
            const float* Wl2 = W_l + (base + 2) * D_ * D_;
            const float* Wr0 = W_r + (base + 0) * D_ * D_;
            const float* Wr1 = W_r + (base + 1) * D_ * D_;
            const float* Wr2 = W_r + (base + 2) * D_ * D_;
            const float* bl0 = b_l + (base + 0) * D_;
            const float* bl1 = b_l + (base + 1) * D_;
            const float* bl2 = b_l + (base + 2) * D_;

            const bool last = (l == NL - 1);
            float* tcui = last ? out_cui : hA_cui;
            float* tvis = last ? out_vis : hA_vis;
            int mode = last ? (f == 0 ? 0 : 3) : 1;  // relu between layers; max for filter 1

            // aggregations (mean over incoming edges)
            agg_mean<<<(NC + 3) / 4, 256, 0, stream>>>(hc, rp_cc, col_cc, agg_a, NC);
            agg_mean<<<(NC + 3) / 4, 256, 0, stream>>>(hv, rp_vc, col_vc, agg_b, NC);
            // combined self-weight: h_cui @ (Wr0 + Wr1)^T
            wadd<<<(D_ * D_ + 255) / 256, 256, 0, stream>>>(Wr0, Wr1, wsum);
            // out_cui = b0+b1 + agg_cc@Wl0^T + agg_vc@Wl1^T + h_cui@(Wr0+Wr1)^T
            gemm_fused<3><<<(NC + 31) / 32, 256, 0, stream>>>(
                agg_a, Wl0, agg_b, Wl1, hc, wsum, bl0, bl1, tcui, NC, mode);
            // out_vis = b2 + agg_cv@Wl2^T + h_vis@Wr2^T   (agg_a reuse after gemm above)
            agg_mean<<<(NV + 3) / 4, 256, 0, stream>>>(hc, rp_cv, col_cv, agg_a, NV);
            gemm_fused<2><<<(NV + 31) / 32, 256, 0, stream>>>(
                agg_a, Wl2, hv, Wr2, nullptr, nullptr, bl2, nullptr, tvis, NV, mode);

            hc = hA_cui;
            hv = hA_vis;
        }
    }
}

// Round 2
// 1264.074 us; speedup vs baseline: 2.0896x; 2.0896x over previous
//
#include <hip/hip_runtime.h>

// ---------------------------------------------------------------------------
// UMLSGraphEmbedding: 2-filter x 2-layer hetero GraphSAGE, D=128.
// Round 1: bf16 datapath + MFMA GEMMs, shared layer-1 aggregation,
// 2-filter-fused layer-1 GEMM, max-RMW epilogue for filter 1.
// ---------------------------------------------------------------------------

constexpr int D_ = 128;
constexpr int SCAN_BLOCK = 256;
constexpr int SCAN_ITEMS = 8;
constexpr int SCAN_CHUNK = SCAN_BLOCK * SCAN_ITEMS; // 2048

typedef __attribute__((ext_vector_type(8))) short bf16x8;
typedef __attribute__((ext_vector_type(4))) float f32x4;

__device__ inline ushort f2bf(float f) {
    uint u = __float_as_uint(f);
    u += 0x7fffu + ((u >> 16) & 1u);   // round-to-nearest-even
    return (ushort)(u >> 16);
}

// ---------------- CSR build (unchanged from round 0, proven) ----------------

__global__ void csr_count(const int* __restrict__ dst, int* __restrict__ cnt, int E) {
    int e = blockIdx.x * 256 + threadIdx.x;
    if (e < E) atomicAdd(&cnt[dst[e]], 1);
}

__global__ void scan_partial(const int* __restrict__ cnt, int* __restrict__ rowptr,
                             int* __restrict__ blockSums, int n) {
    __shared__ int s[SCAN_BLOCK];
    int base = blockIdx.x * SCAN_CHUNK + threadIdx.x * SCAN_ITEMS;
    int v[SCAN_ITEMS];
    int sum = 0;
    #pragma unroll
    for (int i = 0; i < SCAN_ITEMS; ++i) {
        int idx = base + i;
        v[i] = (idx < n) ? cnt[idx] : 0;
        sum += v[i];
    }
    s[threadIdx.x] = sum;
    __syncthreads();
    for (int off = 1; off < SCAN_BLOCK; off <<= 1) {
        int t = (threadIdx.x >= off) ? s[threadIdx.x - off] : 0;
        __syncthreads();
        s[threadIdx.x] += t;
        __syncthreads();
    }
    int excl = s[threadIdx.x] - sum;
    int run = excl;
    #pragma unroll
    for (int i = 0; i < SCAN_ITEMS; ++i) {
        int idx = base + i;
        run += v[i];
        if (idx < n) rowptr[idx + 1] = run;
    }
    if (threadIdx.x == 0) blockSums[blockIdx.x] = s[SCAN_BLOCK - 1];
}

__global__ void scan_blocksums(int* blockSums, int nb) {
    __shared__ int s[SCAN_BLOCK];
    int v = (threadIdx.x < nb) ? blockSums[threadIdx.x] : 0;
    s[threadIdx.x] = v;
    __syncthreads();
    for (int off = 1; off < SCAN_BLOCK; off <<= 1) {
        int t = (threadIdx.x >= off) ? s[threadIdx.x - off] : 0;
        __syncthreads();
        s[threadIdx.x] += t;
        __syncthreads();
    }
    if (threadIdx.x < nb) blockSums[threadIdx.x] = s[threadIdx.x] - v;
}

__global__ void scan_add(int* __restrict__ rowptr, const int* __restrict__ blockSums, int n) {
    int idx = blockIdx.x * blockDim.x + threadIdx.x;
    if (idx < n) rowptr[idx + 1] += blockSums[idx / SCAN_CHUNK];
    if (idx == 0) rowptr[0] = 0;
}

__global__ void csr_fill(const int* __restrict__ src, const int* __restrict__ dst,
                         const int* __restrict__ rowptr, int* __restrict__ fill,
                         int* __restrict__ col, int E) {
    int e = blockIdx.x * 256 + threadIdx.x;
    if (e >= E) return;
    int d = dst[e];
    int pos = rowptr[d] + atomicAdd(&fill[d], 1);
    col[pos] = src[e];
}

// ---------------- f32 -> bf16 convert ----------------

__global__ void cvt_bf16(const float* __restrict__ x, ushort* __restrict__ y, int n) {
    int i = (blockIdx.x * 256 + threadIdx.x) * 4;
    if (i >= n) return;
    float4 v = *(const float4*)(x + i);
    ushort4 o = make_ushort4(f2bf(v.x), f2bf(v.y), f2bf(v.z), f2bf(v.w));
    *(ushort4*)(y + i) = o;
}

// ---------------- weight prep: bf16 convert + Wr0+Wr1 combine + bias combine ----
// Wcui[f][l] = { Wl[f,l,0], Wl[f,l,1], Wr[f,l,0]+Wr[f,l,1] }   (3 x 128 x 128, bf16)
// Wvis[f][l] = { Wl[f,l,2], Wr[f,l,2] }                        (2 x 128 x 128, bf16)
// Bcui[f][l] = bl[f,l,0]+bl[f,l,1]; Bvis[f][l] = bl[f,l,2]     (f32)

__global__ void prep_weights(const float* __restrict__ W_l, const float* __restrict__ b_l,
                             const float* __restrict__ W_r,
                             ushort* __restrict__ Wcui, ushort* __restrict__ Wvis,
                             float* __restrict__ Bcui, float* __restrict__ Bvis) {
    int i = blockIdx.x * 256 + threadIdx.x;
    if (i < 2 * 2 * 3 * 16384) {
        int jk = i & 16383;
        int m  = (i >> 14) % 3;
        int fl = i / (3 * 16384);
        size_t src = (size_t)fl * 3 * 16384 + jk;
        float v;
        if (m == 0)      v = W_l[src];
        else if (m == 1) v = W_l[src + 16384];
        else             v = W_r[src] + W_r[src + 16384];
        Wcui[i] = f2bf(v);
    }
    if (i < 2 * 2 * 2 * 16384) {
        int jk = i & 16383;
        int m  = (i >> 14) & 1;
        int fl = i / (2 * 16384);
        size_t src = (size_t)fl * 3 * 16384 + 2 * 16384 + jk;
        float v = (m == 0) ? W_l[src] : W_r[src];
        Wvis[i] = f2bf(v);
    }
    if (i < 2 * 2 * 128) {
        int j = i & 127, fl = i >> 7;
        Bcui[i] = b_l[fl * 384 + j] + b_l[fl * 384 + 128 + j];
        Bvis[i] = b_l[fl * 384 + 256 + j];
    }
}

// ---------------- mean aggregation over bf16 features ----------------
// one wave per destination row; lane holds 2 of the 128 features (4B load/edge)

__global__ __launch_bounds__(256)
void agg_mean_bf16(const ushort* __restrict__ hsrc, const int* __restrict__ rowptr,
                   const int* __restrict__ col, ushort* __restrict__ agg, int n) {
    int row = blockIdx.x * 4 + (threadIdx.x >> 6);
    if (row >= n) return;
    int lane = threadIdx.x & 63;
    int beg = rowptr[row], end = rowptr[row + 1];
    float ax = 0.f, ay = 0.f;
    int e = beg;
    for (; e + 4 <= end; e += 4) {
        uint v0 = *(const uint*)(hsrc + (size_t)col[e]     * D_ + lane * 2);
        uint v1 = *(const uint*)(hsrc + (size_t)col[e + 1] * D_ + lane * 2);
        uint v2 = *(const uint*)(hsrc + (size_t)col[e + 2] * D_ + lane * 2);
        uint v3 = *(const uint*)(hsrc + (size_t)col[e + 3] * D_ + lane * 2);
        ax += __uint_as_float(v0 << 16) + __uint_as_float(v1 << 16)
            + __uint_as_float(v2 << 16) + __uint_as_float(v3 << 16);
        ay += __uint_as_float(v0 & 0xffff0000u) + __uint_as_float(v1 & 0xffff0000u)
            + __uint_as_float(v2 & 0xffff0000u) + __uint_as_float(v3 & 0xffff0000u);
    }
    for (; e < end; ++e) {
        uint v = *(const uint*)(hsrc + (size_t)col[e] * D_ + lane * 2);
        ax += __uint_as_float(v << 16);
        ay += __uint_as_float(v & 0xffff0000u);
    }
    float inv = 1.f / fmaxf((float)(end - beg), 1.f);
    uint o = (uint)f2bf(ax * inv) | ((uint)f2bf(ay * inv) << 16);
    *(uint*)(agg + (size_t)row * D_ + lane * 2) = o;
}

// ---------------- MFMA fragment loads ----------------
// A (16x32): lane l holds X[row0 + (l&15)][k0 + (l>>4)*8 .. +7]  (16B)
// B (32x16): lane l holds W[j0 + (l&15)][k0 + (l>>4)*8 .. +7]    (16B, W row-major = B^T)
// C/D: col = l&15, row = (l>>4)*4 + reg                          (m89-verified)

__device__ inline bf16x8 loadA(const ushort* __restrict__ X, int row, int koff, int n) {
    bf16x8 a = {0, 0, 0, 0, 0, 0, 0, 0};
    if (row < n) a = *reinterpret_cast<const bf16x8*>(X + (size_t)row * D_ + koff);
    return a;
}

// ---------------- layer-1 GEMM: both filters, shared X, relu, bf16 out --------
// Y_f = relu( B_f + sum_m X_m @ W_f,m^T ), block = 128 rows, wave = 32 rows.

template <int M>
__global__ __launch_bounds__(256)
void gemm2f_relu(const ushort* __restrict__ X0, const ushort* __restrict__ X1,
                 const ushort* __restrict__ X2,
                 const ushort* __restrict__ W0, const ushort* __restrict__ W1,
                 const float* __restrict__ B0, const float* __restrict__ B1,
                 ushort* __restrict__ Y0, ushort* __restrict__ Y1, int n) {
    const int lane = threadIdx.x & 63;
    const int wave = threadIdx.x >> 6;
    const int row0 = blockIdx.x * 128 + wave * 32;
    const int lr = lane & 15;
    const int kg = lane >> 4;

    f32x4 acc[2][2][8];
    #pragma unroll
    for (int jt = 0; jt < 8; ++jt) {
        float b0 = B0[jt * 16 + lr], b1 = B1[jt * 16 + lr];
        #pragma unroll
        for (int s = 0; s < 2; ++s) {
            acc[s][0][jt] = {b0, b0, b0, b0};
            acc[s][1][jt] = {b1, b1, b1, b1};
        }
    }

    const ushort* Xs[3] = {X0, X1, X2};
    #pragma unroll
    for (int m = 0; m < M; ++m) {
        const ushort* __restrict__ X = Xs[m];
        const ushort* __restrict__ w0 = W0 + m * 16384;
        const ushort* __restrict__ w1 = W1 + m * 16384;
        bf16x8 a[2][4];
        #pragma unroll
        for (int s = 0; s < 2; ++s)
            #pragma unroll
            for (int kt = 0; kt < 4; ++kt)
                a[s][kt] = loadA(X, row0 + s * 16 + lr, kt * 32 + kg * 8, n);
        #pragma unroll
        for (int kt = 0; kt < 4; ++kt) {
            #pragma unroll
            for (int jt = 0; jt < 8; ++jt) {
                bf16x8 b0 = *reinterpret_cast<const bf16x8*>(w0 + (jt * 16 + lr) * D_ + kt * 32 + kg * 8);
                acc[0][0][jt] = __builtin_amdgcn_mfma_f32_16x16x32_bf16(a[0][kt], b0, acc[0][0][jt], 0, 0, 0);
                acc[1][0][jt] = __builtin_amdgcn_mfma_f32_16x16x32_bf16(a[1][kt], b0, acc[1][0][jt], 0, 0, 0);
                bf16x8 b1 = *reinterpret_cast<const bf16x8*>(w1 + (jt * 16 + lr) * D_ + kt * 32 + kg * 8);
                acc[0][1][jt] = __builtin_amdgcn_mfma_f32_16x16x32_bf16(a[0][kt], b1, acc[0][1][jt], 0, 0, 0);
                acc[1][1][jt] = __builtin_amdgcn_mfma_f32_16x16x32_bf16(a[1][kt], b1, acc[1][1][jt], 0, 0, 0);
            }
        }
    }

    #pragma unroll
    for (int s = 0; s < 2; ++s) {
        #pragma unroll
        for (int r = 0; r < 4; ++r) {
            int row = row0 + s * 16 + kg * 4 + r;
            if (row >= n) continue;
            #pragma unroll
            for (int jt = 0; jt < 8; ++jt) {
                int colj = jt * 16 + lr;
                Y0[(size_t)row * D_ + colj] = f2bf(fmaxf(acc[s][0][jt][r], 0.f));
                Y1[(size_t)row * D_ + colj] = f2bf(fmaxf(acc[s][1][jt][r], 0.f));
            }
        }
    }
}

// ---------------- layer-2 GEMM: single filter, f32 out, write or max-RMW ------

template <int M, int MODE>  // MODE 0 = write, 1 = max with existing
__global__ __launch_bounds__(256)
void gemm1f(const ushort* __restrict__ X0, const ushort* __restrict__ X1,
            const ushort* __restrict__ X2,
            const ushort* __restrict__ W, const float* __restrict__ B,
            float* __restrict__ Y, int n) {
    const int lane = threadIdx.x & 63;
    const int wave = threadIdx.x >> 6;
    const int row0 = blockIdx.x * 128 + wave * 32;
    const int lr = lane & 15;
    const int kg = lane >> 4;

    f32x4 acc[2][8];
    #pragma unroll
    for (int jt = 0; jt < 8; ++jt) {
        float b = B[jt * 16 + lr];
        acc[0][jt] = {b, b, b, b};
        acc[1][jt] = {b, b, b, b};
    }

    const ushort* Xs[3] = {X0, X1, X2};
    #pragma unroll
    for (int m = 0; m < M; ++m) {
        const ushort* __restrict__ X = Xs[m];
        const ushort* __restrict__ w = W + m * 16384;
        bf16x8 a[2][4];
        #pragma unroll
        for (int s = 0; s < 2; ++s)
            #pragma unroll
            for (int kt = 0; kt < 4; ++kt)
                a[s][kt] = loadA(X, row0 + s * 16 + lr, kt * 32 + kg * 8, n);
        #pragma unroll
        for (int kt = 0; kt < 4; ++kt) {
            #pragma unroll
            for (int jt = 0; jt < 8; ++jt) {
                bf16x8 b = *reinterpret_cast<const bf16x8*>(w + (jt * 16 + lr) * D_ + kt * 32 + kg * 8);
                acc[0][jt] = __builtin_amdgcn_mfma_f32_16x16x32_bf16(a[0][kt], b, acc[0][jt], 0, 0, 0);
                acc[1][jt] = __builtin_amdgcn_mfma_f32_16x16x32_bf16(a[1][kt], b, acc[1][jt], 0, 0, 0);
            }
        }
    }

    #pragma unroll
    for (int s = 0; s < 2; ++s) {
        #pragma unroll
        for (int r = 0; r < 4; ++r) {
            int row = row0 + s * 16 + kg * 4 + r;
            if (row >= n) continue;
            #pragma unroll
            for (int jt = 0; jt < 8; ++jt) {
                int colj = jt * 16 + lr;
                float v = acc[s][jt][r];
                if (MODE == 1) v = fmaxf(v, Y[(size_t)row * D_ + colj]);
                Y[(size_t)row * D_ + colj] = v;
            }
        }
    }
}

// ---------------------------------------------------------------------------

extern "C" void kernel_launch(void* const* d_in, const int* in_sizes, int n_in,
                              void* d_out, int out_size, void* d_ws, size_t ws_size,
                              hipStream_t stream) {
    const float* x_cui = (const float*)d_in[0];
    const float* x_vis = (const float*)d_in[1];
    const float* W_l   = (const float*)d_in[2];
    const float* b_l   = (const float*)d_in[3];
    const float* W_r   = (const float*)d_in[4];
    const int*   ei_cc = (const int*)d_in[5];
    const int*   ei_vc = (const int*)d_in[6];
    const int*   ei_cv = (const int*)d_in[7];

    const int NC  = in_sizes[0] / D_;
    const int NV  = in_sizes[1] / D_;
    const int ECC = in_sizes[5] / 2;
    const int EVC = in_sizes[6] / 2;
    const int ECV = in_sizes[7] / 2;

    // ---- workspace bump allocator ----
    char* ws = (char*)d_ws;
    size_t off = 0;
    auto alloc = [&](size_t bytes) -> char* {
        char* p = ws + off;
        off += (bytes + 511) & ~(size_t)511;
        return p;
    };
    int* rp_cc  = (int*)alloc((size_t)(NC + 1) * 4);
    int* rp_vc  = (int*)alloc((size_t)(NC + 1) * 4);
    int* rp_cv  = (int*)alloc((size_t)(NV + 1) * 4);
    int* col_cc = (int*)alloc((size_t)ECC * 4);
    int* col_vc = (int*)alloc((size_t)EVC * 4);
    int* col_cv = (int*)alloc((size_t)ECV * 4);
    int* cnt    = (int*)alloc((size_t)(NC + 1) * 4);
    int* bsums  = (int*)alloc(1024);
    ushort* Wcui = (ushort*)alloc((size_t)2 * 2 * 3 * 16384 * 2);
    ushort* Wvis = (ushort*)alloc((size_t)2 * 2 * 2 * 16384 * 2);
    float*  Bcui = (float*)alloc((size_t)2 * 2 * 128 * 4);
    float*  Bvis = (float*)alloc((size_t)2 * 2 * 128 * 4);
    ushort* xc16 = (ushort*)alloc((size_t)NC * D_ * 2);
    ushort* xv16 = (ushort*)alloc((size_t)NV * D_ * 2);
    ushort* h1c0 = (ushort*)alloc((size_t)NC * D_ * 2);
    ushort* h1c1 = (ushort*)alloc((size_t)NC * D_ * 2);
    ushort* h1v0 = (ushort*)alloc((size_t)NV * D_ * 2);
    ushort* h1v1 = (ushort*)alloc((size_t)NV * D_ * 2);
    ushort* aggA = (ushort*)alloc((size_t)NC * D_ * 2);
    ushort* aggB = (ushort*)alloc((size_t)NC * D_ * 2);
    ushort* aggV = (ushort*)alloc((size_t)NV * D_ * 2);
    (void)ws_size;

    // ---- converts + weight prep ----
    cvt_bf16<<<(NC * D_ / 4 + 255) / 256, 256, 0, stream>>>(x_cui, xc16, NC * D_);
    cvt_bf16<<<(NV * D_ / 4 + 255) / 256, 256, 0, stream>>>(x_vis, xv16, NV * D_);
    prep_weights<<<768, 256, 0, stream>>>(W_l, b_l, W_r, Wcui, Wvis, Bcui, Bvis);

    // ---- CSR build (edges layer/filter invariant) ----
    auto build_csr = [&](const int* ei, int E, int n_dst, int* rowptr, int* colbuf) {
        const int* src = ei;
        const int* dst = ei + E;
        hipMemsetAsync(cnt, 0, (size_t)n_dst * 4, stream);
        csr_count<<<(E + 255) / 256, 256, 0, stream>>>(dst, cnt, E);
        int nb = (n_dst + SCAN_CHUNK - 1) / SCAN_CHUNK;
        scan_partial<<<nb, SCAN_BLOCK, 0, stream>>>(cnt, rowptr, bsums, n_dst);
        scan_blocksums<<<1, SCAN_BLOCK, 0, stream>>>(bsums, nb);
        scan_add<<<(n_dst + 255) / 256, 256, 0, stream>>>(rowptr, bsums, n_dst);
        hipMemsetAsync(cnt, 0, (size_t)n_dst * 4, stream);
        csr_fill<<<(E + 255) / 256, 256, 0, stream>>>(src, dst, rowptr, cnt, colbuf, E);
    };
    build_csr(ei_cc, ECC, NC, rp_cc, col_cc);
    build_csr(ei_vc, EVC, NC, rp_vc, col_vc);
    build_csr(ei_cv, ECV, NV, rp_cv, col_cv);

    float* out_cui = (float*)d_out;
    float* out_vis = (float*)d_out + (size_t)NC * D_;

    const int gC = (NC + 127) / 128;
    const int gV = (NV + 127) / 128;

    // ---- layer 1: aggregations shared across filters ----
    agg_mean_bf16<<<(NC + 3) / 4, 256, 0, stream>>>(xc16, rp_cc, col_cc, aggA, NC);
    agg_mean_bf16<<<(NC + 3) / 4, 256, 0, stream>>>(xv16, rp_vc, col_vc, aggB, NC);
    agg_mean_bf16<<<(NV + 3) / 4, 256, 0, stream>>>(xc16, rp_cv, col_cv, aggV, NV);

    // ---- layer 1 GEMMs: both filters fused, relu, bf16 out ----
    gemm2f_relu<3><<<gC, 256, 0, stream>>>(aggA, aggB, xc16,
        Wcui + (size_t)0 * 3 * 16384, Wcui + (size_t)2 * 3 * 16384,
        Bcui + 0 * 128, Bcui + 2 * 128, h1c0, h1c1, NC);
    gemm2f_relu<2><<<gV, 256, 0, stream>>>(aggV, xv16, nullptr,
        Wvis + (size_t)0 * 2 * 16384, Wvis + (size_t)2 * 2 * 16384,
        Bvis + 0 * 128, Bvis + 2 * 128, h1v0, h1v1, NV);

    // ---- layer 2: per filter (agg buffers reused), write then max-RMW ----
    // filter 0
    agg_mean_bf16<<<(NC + 3) / 4, 256, 0, stream>>>(h1c0, rp_cc, col_cc, aggA, NC);
    agg_mean_bf16<<<(NC + 3) / 4, 256, 0, stream>>>(h1v0, rp_vc, col_vc, aggB, NC);
    agg_mean_bf16<<<(NV + 3) / 4, 256, 0, stream>>>(h1c0, rp_cv, col_cv, aggV, NV);
    gemm1f<3, 0><<<gC, 256, 0, stream>>>(aggA, aggB, h1c0,
        Wcui + (size_t)1 * 3 * 16384, Bcui + 1 * 128, out_cui, NC);
    gemm1f<2, 0><<<gV, 256, 0, stream>>>(aggV, h1v0, nullptr,
        Wvis + (size_t)1 * 2 * 16384, Bvis + 1 * 128, out_vis, NV);
    // filter 1
    agg_mean_bf16<<<(NC + 3) / 4, 256, 0, stream>>>(h1c1, rp_cc, col_cc, aggA, NC);
    agg_mean_bf16<<<(NC + 3) / 4, 256, 0, stream>>>(h1v1, rp_vc, col_vc, aggB, NC);
    agg_mean_bf16<<<(NV + 3) / 4, 256, 0, stream>>>(h1c1, rp_cv, col_cv, aggV, NV);
    gemm1f<3, 1><<<gC, 256, 0, stream>>>(aggA, aggB, h1c1,
        Wcui + (size_t)3 * 3 * 16384, Bcui + 3 * 128, out_cui, NC);
    gemm1f<2, 1><<<gV, 256, 0, stream>>>(aggV, h1v1, nullptr,
        Wvis + (size_t)3 * 2 * 16384, Bvis + 3 * 128, out_vis, NV);
}

// Round 3
// 1042.612 us; speedup vs baseline: 2.5334x; 1.2124x over previous
//
#include <hip/hip_runtime.h>

// ---------------------------------------------------------------------------
// UMLSGraphEmbedding: 2-filter x 2-layer hetero GraphSAGE, D=128.
// Round 2: register-resident fragment-linear weights, grid-stride GEMM,
// in-kernel filter-max epilogue, paired layer-2 aggregation.
// ---------------------------------------------------------------------------

constexpr int D_ = 128;
constexpr int SCAN_BLOCK = 256;
constexpr int SCAN_ITEMS = 8;
constexpr int SCAN_CHUNK = SCAN_BLOCK * SCAN_ITEMS; // 2048

typedef __attribute__((ext_vector_type(8))) short bf16x8;
typedef __attribute__((ext_vector_type(4))) float f32x4;

__device__ inline ushort f2bf(float f) {
    uint u = __float_as_uint(f);
    u += 0x7fffu + ((u >> 16) & 1u);   // round-to-nearest-even
    return (ushort)(u >> 16);
}

// ---------------- CSR build (proven) ----------------

__global__ void csr_count(const int* __restrict__ dst, int* __restrict__ cnt, int E) {
    int e = blockIdx.x * 256 + threadIdx.x;
    if (e < E) atomicAdd(&cnt[dst[e]], 1);
}

__global__ void scan_partial(const int* __restrict__ cnt, int* __restrict__ rowptr,
                             int* __restrict__ blockSums, int n) {
    __shared__ int s[SCAN_BLOCK];
    int base = blockIdx.x * SCAN_CHUNK + threadIdx.x * SCAN_ITEMS;
    int v[SCAN_ITEMS];
    int sum = 0;
    #pragma unroll
    for (int i = 0; i < SCAN_ITEMS; ++i) {
        int idx = base + i;
        v[i] = (idx < n) ? cnt[idx] : 0;
        sum += v[i];
    }
    s[threadIdx.x] = sum;
    __syncthreads();
    for (int off = 1; off < SCAN_BLOCK; off <<= 1) {
        int t = (threadIdx.x >= off) ? s[threadIdx.x - off] : 0;
        __syncthreads();
        s[threadIdx.x] += t;
        __syncthreads();
    }
    int excl = s[threadIdx.x] - sum;
    int run = excl;
    #pragma unroll
    for (int i = 0; i < SCAN_ITEMS; ++i) {
        int idx = base + i;
        run += v[i];
        if (idx < n) rowptr[idx + 1] = run;
    }
    if (threadIdx.x == 0) blockSums[blockIdx.x] = s[SCAN_BLOCK - 1];
}

__global__ void scan_blocksums(int* blockSums, int nb) {
    __shared__ int s[SCAN_BLOCK];
    int v = (threadIdx.x < nb) ? blockSums[threadIdx.x] : 0;
    s[threadIdx.x] = v;
    __syncthreads();
    for (int off = 1; off < SCAN_BLOCK; off <<= 1) {
        int t = (threadIdx.x >= off) ? s[threadIdx.x - off] : 0;
        __syncthreads();
        s[threadIdx.x] += t;
        __syncthreads();
    }
    if (threadIdx.x < nb) blockSums[threadIdx.x] = s[threadIdx.x] - v;
}

__global__ void scan_add(int* __restrict__ rowptr, const int* __restrict__ blockSums, int n) {
    int idx = blockIdx.x * blockDim.x + threadIdx.x;
    if (idx < n) rowptr[idx + 1] += blockSums[idx / SCAN_CHUNK];
    if (idx == 0) rowptr[0] = 0;
}

__global__ void csr_fill(const int* __restrict__ src, const int* __restrict__ dst,
                         const int* __restrict__ rowptr, int* __restrict__ fill,
                         int* __restrict__ col, int E) {
    int e = blockIdx.x * 256 + threadIdx.x;
    if (e >= E) return;
    int d = dst[e];
    int pos = rowptr[d] + atomicAdd(&fill[d], 1);
    col[pos] = src[e];
}

// ---------------- f32 -> bf16 convert ----------------

__global__ void cvt_bf16(const float* __restrict__ x, ushort* __restrict__ y, int n) {
    int i = (blockIdx.x * 256 + threadIdx.x) * 4;
    if (i >= n) return;
    float4 v = *(const float4*)(x + i);
    ushort4 o = make_ushort4(f2bf(v.x), f2bf(v.y), f2bf(v.z), f2bf(v.w));
    *(ushort4*)(y + i) = o;
}

// ---------------- weight prep: fragment-linear bf16 layout ----------------
// B-frag for MFMA: lane l holds W[jt*16+(l&15)][kt*32+(l>>4)*8 .. +7].
// Storage: cui  [fl][m(3)][kt][jt][lane][8]  (fl = f*2+l)
//          vis  [fl][m(2)][kt][jt][lane][8]
// m=2 (cui) is Wr0+Wr1 combined; vis m=1 is Wr2.

constexpr int FC_CUI = 2 * 2 * 3 * 4 * 8 * 64;  // 24576 threads
constexpr int FC_VIS = 2 * 2 * 2 * 4 * 8 * 64;  // 16384 threads

__global__ void prep_frag(const float* __restrict__ W_l, const float* __restrict__ b_l,
                          const float* __restrict__ W_r,
                          ushort* __restrict__ Wcui, ushort* __restrict__ Wvis,
                          float* __restrict__ Bcui, float* __restrict__ Bvis) {
    int t = blockIdx.x * 256 + threadIdx.x;
    if (t < FC_CUI) {
        int lane = t & 63, jt = (t >> 6) & 7, kt = (t >> 9) & 3;
        int q = t >> 11; int m = q % 3, fl = q / 3;
        int j = jt * 16 + (lane & 15);
        int k0 = kt * 32 + (lane >> 4) * 8;
        size_t b0 = (size_t)(fl * 3) * 16384 + (size_t)j * 128 + k0;
        ushort* dst = Wcui + (size_t)t * 8;
        #pragma unroll
        for (int i = 0; i < 8; ++i) {
            float v;
            if (m == 0)      v = W_l[b0 + i];
            else if (m == 1) v = W_l[b0 + 16384 + i];
            else             v = W_r[b0 + i] + W_r[b0 + 16384 + i];
            dst[i] = f2bf(v);
        }
        return;
    }
    int s = t - FC_CUI;
    if (s < FC_VIS) {
        int lane = s & 63, jt = (s >> 6) & 7, kt = (s >> 9) & 3;
        int q = s >> 11; int m = q & 1, fl = q >> 1;
        int j = jt * 16 + (lane & 15);
        int k0 = kt * 32 + (lane >> 4) * 8;
        size_t b0 = (size_t)(fl * 3 + 2) * 16384 + (size_t)j * 128 + k0;
        ushort* dst = Wvis + (size_t)s * 8;
        #pragma unroll
        for (int i = 0; i < 8; ++i) {
            float v = (m == 0) ? W_l[b0 + i] : W_r[b0 + i];
            dst[i] = f2bf(v);
        }
        return;
    }
    int u = s - FC_VIS;
    if (u < 512) {           // Bcui[fl*128 + j] = bl0 + bl1
        int j = u & 127, fl = u >> 7;
        Bcui[u] = b_l[fl * 384 + j] + b_l[fl * 384 + 128 + j];
        return;
    }
    u -= 512;
    if (u < 512) {           // Bvis[fl*128 + j] = bl2
        int j = u & 127, fl = u >> 7;
        Bvis[u] = b_l[fl * 384 + 256 + j];
    }
}

// ---------------- mean aggregation (bf16), one wave per dst row ----------------

__global__ __launch_bounds__(256)
void agg1(const ushort* __restrict__ hsrc, const int* __restrict__ rowptr,
          const int* __restrict__ col, ushort* __restrict__ agg, int n) {
    int row = blockIdx.x * 4 + (threadIdx.x >> 6);
    if (row >= n) return;
    int lane = threadIdx.x & 63;
    int beg = rowptr[row], end = rowptr[row + 1];
    float ax = 0.f, ay = 0.f;
    int e = beg;
    for (; e + 8 <= end; e += 8) {
        uint u[8];
        #pragma unroll
        for (int i = 0; i < 8; ++i)
            u[i] = *(const uint*)(hsrc + (size_t)col[e + i] * D_ + lane * 2);
        #pragma unroll
        for (int i = 0; i < 8; ++i) {
            ax += __uint_as_float(u[i] << 16);
            ay += __uint_as_float(u[i] & 0xffff0000u);
        }
    }
    for (; e < end; ++e) {
        uint v = *(const uint*)(hsrc + (size_t)col[e] * D_ + lane * 2);
        ax += __uint_as_float(v << 16);
        ay += __uint_as_float(v & 0xffff0000u);
    }
    float inv = 1.f / fmaxf((float)(end - beg), 1.f);
    uint o = (uint)f2bf(ax * inv) | ((uint)f2bf(ay * inv) << 16);
    *(uint*)(agg + (size_t)row * D_ + lane * 2) = o;
}

// paired: gather from two tables per edge (layer-2 filters share edge walk)
__global__ __launch_bounds__(256)
void agg2(const ushort* __restrict__ s0, const ushort* __restrict__ s1,
          const int* __restrict__ rowptr, const int* __restrict__ col,
          ushort* __restrict__ d0, ushort* __restrict__ d1, int n) {
    int row = blockIdx.x * 4 + (threadIdx.x >> 6);
    if (row >= n) return;
    int lane = threadIdx.x & 63;
    int beg = rowptr[row], end = rowptr[row + 1];
    float a0x = 0.f, a0y = 0.f, a1x = 0.f, a1y = 0.f;
    int e = beg;
    for (; e + 4 <= end; e += 4) {
        uint u0[4], u1[4];
        #pragma unroll
        for (int i = 0; i < 4; ++i) {
            size_t o = (size_t)col[e + i] * D_ + lane * 2;
            u0[i] = *(const uint*)(s0 + o);
            u1[i] = *(const uint*)(s1 + o);
        }
        #pragma unroll
        for (int i = 0; i < 4; ++i) {
            a0x += __uint_as_float(u0[i] << 16);
            a0y += __uint_as_float(u0[i] & 0xffff0000u);
            a1x += __uint_as_float(u1[i] << 16);
            a1y += __uint_as_float(u1[i] & 0xffff0000u);
        }
    }
    for (; e < end; ++e) {
        size_t o = (size_t)col[e] * D_ + lane * 2;
        uint u0 = *(const uint*)(s0 + o);
        uint u1 = *(const uint*)(s1 + o);
        a0x += __uint_as_float(u0 << 16);
        a0y += __uint_as_float(u0 & 0xffff0000u);
        a1x += __uint_as_float(u1 << 16);
        a1y += __uint_as_float(u1 & 0xffff0000u);
    }
    float inv = 1.f / fmaxf((float)(end - beg), 1.f);
    size_t oo = (size_t)row * D_ + lane * 2;
    *(uint*)(d0 + oo) = (uint)f2bf(a0x * inv) | ((uint)f2bf(a0y * inv) << 16);
    *(uint*)(d1 + oo) = (uint)f2bf(a1x * inv) | ((uint)f2bf(a1y * inv) << 16);
}

// ---------------- GEMM: register-resident W fragments, grid-stride rows ------
// 512 threads = 8 waves. wave w: filter f = w>>2, cols [ (w&3)*32, +32 ).
// Per 32-row tile: 24 A-loads (16B/lane), 48 MFMA (M=3). No LDS for EPI=0.
// EPI=0: relu -> bf16 to Y0/Y1 (per filter).  EPI=1: max over filters -> f32 Yf.

template <int M, int EPI>
__global__ __launch_bounds__(512, 2)
void gemm_frag(const ushort* __restrict__ X00, const ushort* __restrict__ X01,
               const ushort* __restrict__ X02,
               const ushort* __restrict__ X10, const ushort* __restrict__ X11,
               const ushort* __restrict__ X12,
               const ushort* __restrict__ Wlin, int wstride,
               const float* __restrict__ Bb, int bstride,
               ushort* __restrict__ Y0, ushort* __restrict__ Y1,
               float* __restrict__ Yf, int n, int ntiles) {
    __shared__ float lds[32 * 128];   // used by EPI=1 only (16KB)
    const int lane = threadIdx.x & 63;
    const int w = threadIdx.x >> 6;
    const int f = w >> 2;
    const int jt0 = (w & 3) * 2;
    const int lr = lane & 15, kg = lane >> 4;

    // load B fragments once per block (register-resident weights)
    bf16x8 breg[M][4][2];
    const ushort* wf = Wlin + (size_t)f * wstride;
    #pragma unroll
    for (int m = 0; m < M; ++m)
        #pragma unroll
        for (int kt = 0; kt < 4; ++kt)
            #pragma unroll
            for (int j = 0; j < 2; ++j) {
                int fi = (m * 4 + kt) * 8 + (jt0 + j);
                breg[m][kt][j] = *reinterpret_cast<const bf16x8*>(wf + ((size_t)fi * 64 + lane) * 8);
            }

    const float bb0 = Bb[f * bstride + (jt0 + 0) * 16 + lr];
    const float bb1 = Bb[f * bstride + (jt0 + 1) * 16 + lr];
    const ushort* Xf[3] = { f ? X10 : X00, f ? X11 : X01, f ? X12 : X02 };

    const bf16x8 zero = {0, 0, 0, 0, 0, 0, 0, 0};

    for (int tile = blockIdx.x; tile < ntiles; tile += gridDim.x) {
        const int row0 = tile * 32;
        f32x4 acc[2][2];
        #pragma unroll
        for (int s = 0; s < 2; ++s)
            #pragma unroll
            for (int r = 0; r < 4; ++r) {
                acc[s][0][r] = bb0;
                acc[s][1][r] = bb1;
            }

        #pragma unroll
        for (int m = 0; m < M; ++m) {
            bf16x8 a[2][4];
            #pragma unroll
            for (int s = 0; s < 2; ++s) {
                int row = row0 + s * 16 + lr;
                const ushort* p = Xf[m] + (size_t)row * D_ + kg * 8;
                bool ok = row < n;
                #pragma unroll
                for (int kt = 0; kt < 4; ++kt)
                    a[s][kt] = ok ? *reinterpret_cast<const bf16x8*>(p + kt * 32) : zero;
            }
            #pragma unroll
            for (int kt = 0; kt < 4; ++kt)
                #pragma unroll
                for (int s = 0; s < 2; ++s) {
                    acc[s][0] = __builtin_amdgcn_mfma_f32_16x16x32_bf16(a[s][kt], breg[m][kt][0], acc[s][0], 0, 0, 0);
                    acc[s][1] = __builtin_amdgcn_mfma_f32_16x16x32_bf16(a[s][kt], breg[m][kt][1], acc[s][1], 0, 0, 0);
                }
        }

        if (EPI == 0) {
            ushort* Y = f ? Y1 : Y0;
            #pragma unroll
            for (int s = 0; s < 2; ++s)
                #pragma unroll
                for (int r = 0; r < 4; ++r) {
                    int row = row0 + s * 16 + kg * 4 + r;
                    if (row >= n) continue;
                    #pragma unroll
                    for (int j = 0; j < 2; ++j)
                        Y[(size_t)row * D_ + (jt0 + j) * 16 + lr] = f2bf(fmaxf(acc[s][j][r], 0.f));
                }
        } else {
            if (f == 1) {
                #pragma unroll
                for (int s = 0; s < 2; ++s)
                    #pragma unroll
                    for (int r = 0; r < 4; ++r)
                        #pragma unroll
                        for (int j = 0; j < 2; ++j)
                            lds[(s * 16 + kg * 4 + r) * 128 + (jt0 + j) * 16 + lr] = acc[s][j][r];
            }
            __syncthreads();
            if (f == 0) {
                #pragma unroll
                for (int s = 0; s < 2; ++s)
                    #pragma unroll
                    for (int r = 0; r < 4; ++r) {
                        int rt = s * 16 + kg * 4 + r;
                        int row = row0 + rt;
                        if (row >= n) continue;
                        #pragma unroll
                        for (int j = 0; j < 2; ++j) {
                            int c = (jt0 + j) * 16 + lr;
                            Yf[(size_t)row * D_ + c] = fmaxf(acc[s][j][r], lds[rt * 128 + c]);
                        }
                    }
            }
            __syncthreads();
        }
    }
}

// ---------------------------------------------------------------------------

extern "C" void kernel_launch(void* const* d_in, const int* in_sizes, int n_in,
                              void* d_out, int out_size, void* d_ws, size_t ws_size,
                              hipStream_t stream) {
    const float* x_cui = (const float*)d_in[0];
    const float* x_vis = (const float*)d_in[1];
    const float* W_l   = (const float*)d_in[2];
    const float* b_l   = (const float*)d_in[3];
    const float* W_r   = (const float*)d_in[4];
    const int*   ei_cc = (const int*)d_in[5];
    const int*   ei_vc = (const int*)d_in[6];
    const int*   ei_cv = (const int*)d_in[7];

    const int NC  = in_sizes[0] / D_;
    const int NV  = in_sizes[1] / D_;
    const int ECC = in_sizes[5] / 2;
    const int EVC = in_sizes[6] / 2;
    const int ECV = in_sizes[7] / 2;

    // ---- workspace bump allocator ----
    char* ws = (char*)d_ws;
    size_t off = 0;
    auto alloc = [&](size_t bytes) -> char* {
        char* p = ws + off;
        off += (bytes + 511) & ~(size_t)511;
        return p;
    };
    int* rp_cc  = (int*)alloc((size_t)(NC + 1) * 4);
    int* rp_vc  = (int*)alloc((size_t)(NC + 1) * 4);
    int* rp_cv  = (int*)alloc((size_t)(NV + 1) * 4);
    int* col_cc = (int*)alloc((size_t)ECC * 4);
    int* col_vc = (int*)alloc((size_t)EVC * 4);
    int* col_cv = (int*)alloc((size_t)ECV * 4);
    int* cnt    = (int*)alloc((size_t)(NC + 1) * 4);
    int* bsums  = (int*)alloc(1024);
    ushort* Wcui_lin = (ushort*)alloc((size_t)FC_CUI * 8 * 2);
    ushort* Wvis_lin = (ushort*)alloc((size_t)FC_VIS * 8 * 2);
    float*  Bcui = (float*)alloc(512 * 4);
    float*  Bvis = (float*)alloc(512 * 4);
    ushort* xc16 = (ushort*)alloc((size_t)NC * D_ * 2);
    ushort* xv16 = (ushort*)alloc((size_t)NV * D_ * 2);
    ushort* h1c0 = (ushort*)alloc((size_t)NC * D_ * 2);
    ushort* h1c1 = (ushort*)alloc((size_t)NC * D_ * 2);
    ushort* h1v0 = (ushort*)alloc((size_t)NV * D_ * 2);
    ushort* h1v1 = (ushort*)alloc((size_t)NV * D_ * 2);
    ushort* aggA = (ushort*)alloc((size_t)NC * D_ * 2);
    ushort* aggB = (ushort*)alloc((size_t)NC * D_ * 2);
    ushort* aggC = (ushort*)alloc((size_t)NC * D_ * 2);
    ushort* aggV = (ushort*)alloc((size_t)NV * D_ * 2);
    (void)ws_size;

    // ---- converts + weight prep ----
    cvt_bf16<<<(NC * D_ / 4 + 255) / 256, 256, 0, stream>>>(x_cui, xc16, NC * D_);
    cvt_bf16<<<(NV * D_ / 4 + 255) / 256, 256, 0, stream>>>(x_vis, xv16, NV * D_);
    prep_frag<<<(FC_CUI + FC_VIS + 1024 + 255) / 256, 256, 0, stream>>>(
        W_l, b_l, W_r, Wcui_lin, Wvis_lin, Bcui, Bvis);

    // ---- CSR build ----
    auto build_csr = [&](const int* ei, int E, int n_dst, int* rowptr, int* colbuf) {
        const int* src = ei;
        const int* dst = ei + E;
        hipMemsetAsync(cnt, 0, (size_t)n_dst * 4, stream);
        csr_count<<<(E + 255) / 256, 256, 0, stream>>>(dst, cnt, E);
        int nb = (n_dst + SCAN_CHUNK - 1) / SCAN_CHUNK;
        scan_partial<<<nb, SCAN_BLOCK, 0, stream>>>(cnt, rowptr, bsums, n_dst);
        scan_blocksums<<<1, SCAN_BLOCK, 0, stream>>>(bsums, nb);
        scan_add<<<(n_dst + 255) / 256, 256, 0, stream>>>(rowptr, bsums, n_dst);
        hipMemsetAsync(cnt, 0, (size_t)n_dst * 4, stream);
        csr_fill<<<(E + 255) / 256, 256, 0, stream>>>(src, dst, rowptr, cnt, colbuf, E);
    };
    build_csr(ei_cc, ECC, NC, rp_cc, col_cc);
    build_csr(ei_vc, EVC, NC, rp_vc, col_vc);
    build_csr(ei_cv, ECV, NV, rp_cv, col_cv);

    float* out_cui = (float*)d_out;
    float* out_vis = (float*)d_out + (size_t)NC * D_;

    const int ntC = (NC + 31) / 32;   // 3125
    const int ntV = (NV + 31) / 32;   // 1563
    const int GEMM_GRID = 256;

    // strides within fragment-linear buffers (elements)
    const int wstrC = 2 * 3 * 16384;  // filter stride, cui
    const int wstrV = 2 * 2 * 16384;  // filter stride, vis

    // ---- layer 1: shared aggregations, both filters in one GEMM ----
    agg1<<<(NC + 3) / 4, 256, 0, stream>>>(xc16, rp_cc, col_cc, aggA, NC);
    agg1<<<(NC + 3) / 4, 256, 0, stream>>>(xv16, rp_vc, col_vc, aggB, NC);
    agg1<<<(NV + 3) / 4, 256, 0, stream>>>(xc16, rp_cv, col_cv, aggV, NV);

    gemm_frag<3, 0><<<GEMM_GRID, 512, 0, stream>>>(
        aggA, aggB, xc16, aggA, aggB, xc16,
        Wcui_lin /*layer0*/, wstrC, Bcui /*layer0*/, 256,
        h1c0, h1c1, nullptr, NC, ntC);
    gemm_frag<2, 0><<<GEMM_GRID, 512, 0, stream>>>(
        aggV, xv16, nullptr, aggV, xv16, nullptr,
        Wvis_lin, wstrV, Bvis, 256,
        h1v0, h1v1, nullptr, NV, ntV);

    // ---- layer 2: paired aggregations, fused filter-max GEMM -> d_out ----
    agg2<<<(NC + 3) / 4, 256, 0, stream>>>(h1c0, h1c1, rp_cc, col_cc, aggA, xc16, NC);
    agg2<<<(NC + 3) / 4, 256, 0, stream>>>(h1v0, h1v1, rp_vc, col_vc, aggB, aggC, NC);
    agg2<<<(NV + 3) / 4, 256, 0, stream>>>(h1c0, h1c1, rp_cv, col_cv, aggV, xv16, NV);

    gemm_frag<3, 1><<<GEMM_GRID, 512, 0, stream>>>(
        aggA, aggB, h1c0, xc16, aggC, h1c1,
        Wcui_lin + 3 * 16384 /*layer1*/, wstrC, Bcui + 128, 256,
        nullptr, nullptr, out_cui, NC, ntC);
    gemm_frag<2, 1><<<GEMM_GRID, 512, 0, stream>>>(
        aggV, h1v0, nullptr, xv16, h1v1, nullptr,
        Wvis_lin + 2 * 16384, wstrV, Bvis + 128, 256,
        nullptr, nullptr, out_vis, NV, ntV);
}

// Round 4
// 944.020 us; speedup vs baseline: 2.7980x; 1.1044x over previous
//
#include <hip/hip_runtime.h>

// ---------------------------------------------------------------------------
// UMLSGraphEmbedding: 2-filter x 2-layer hetero GraphSAGE, D=128.
// Round 3: 16B-vectorized gathers (16 lanes/row), pair-interleaved L2 tables,
// fused agg/gemm/csr dispatches, GEMM grid fixed to fill the machine.
// ---------------------------------------------------------------------------

constexpr int D_ = 128;
constexpr int SCAN_BLOCK = 256;
constexpr int SCAN_ITEMS = 8;
constexpr int SCAN_CHUNK = SCAN_BLOCK * SCAN_ITEMS; // 2048

typedef __attribute__((ext_vector_type(8))) short bf16x8;
typedef __attribute__((ext_vector_type(8))) ushort u16x8;
typedef __attribute__((ext_vector_type(4))) float f32x4;

__device__ inline ushort f2bf(float f) {
    uint u = __float_as_uint(f);
    u += 0x7fffu + ((u >> 16) & 1u);   // round-to-nearest-even
    return (ushort)(u >> 16);
}

__device__ inline void acc8(float a[8], bf16x8 v) {
    #pragma unroll
    for (int i = 0; i < 8; ++i)
        a[i] += __uint_as_float(((uint)(ushort)v[i]) << 16);
}

__device__ inline u16x8 packbf(const float a[8], float inv) {
    u16x8 o;
    #pragma unroll
    for (int i = 0; i < 8; ++i) o[i] = f2bf(a[i] * inv);
    return o;
}

// ======================= CSR build (fused 3 edge types) ======================

struct EdgeJob {
    const int* src; const int* dst; const int* rowptr;
    int* cnt; int* col; int E; int blk0;
};

__global__ __launch_bounds__(256)
void count3(EdgeJob a, EdgeJob b, EdgeJob c) {
    const EdgeJob& j = ((int)blockIdx.x >= c.blk0) ? c :
                       ((int)blockIdx.x >= b.blk0) ? b : a;
    int e = (blockIdx.x - j.blk0) * 256 + threadIdx.x;
    if (e < j.E) atomicAdd(&j.cnt[j.dst[e]], 1);
}

__global__ __launch_bounds__(256)
void fill3(EdgeJob a, EdgeJob b, EdgeJob c) {
    const EdgeJob& j = ((int)blockIdx.x >= c.blk0) ? c :
                       ((int)blockIdx.x >= b.blk0) ? b : a;
    int e = (blockIdx.x - j.blk0) * 256 + threadIdx.x;
    if (e >= j.E) return;
    int d = j.dst[e];
    int pos = j.rowptr[d] + atomicAdd(&j.cnt[d], 1);
    j.col[pos] = j.src[e];
}

struct ScanJob {
    const int* cnt; int* rowptr; int* bsums;
    int n; int nbp; int blk0p; int blk0a;
};

__global__ __launch_bounds__(256)
void scanP3(ScanJob a, ScanJob b, ScanJob c) {
    const ScanJob& j = ((int)blockIdx.x >= c.blk0p) ? c :
                       ((int)blockIdx.x >= b.blk0p) ? b : a;
    int blk = blockIdx.x - j.blk0p;
    __shared__ int s[SCAN_BLOCK];
    int base = blk * SCAN_CHUNK + threadIdx.x * SCAN_ITEMS;
    int v[SCAN_ITEMS];
    int sum = 0;
    #pragma unroll
    for (int i = 0; i < SCAN_ITEMS; ++i) {
        int idx = base + i;
        v[i] = (idx < j.n) ? j.cnt[idx] : 0;
        sum += v[i];
    }
    s[threadIdx.x] = sum;
    __syncthreads();
    for (int off = 1; off < SCAN_BLOCK; off <<= 1) {
        int t = (threadIdx.x >= off) ? s[threadIdx.x - off] : 0;
        __syncthreads();
        s[threadIdx.x] += t;
        __syncthreads();
    }
    int run = s[threadIdx.x] - sum;
    #pragma unroll
    for (int i = 0; i < SCAN_ITEMS; ++i) {
        int idx = base + i;
        run += v[i];
        if (idx < j.n) j.rowptr[idx + 1] = run;
    }
    if (threadIdx.x == 0) j.bsums[blk] = s[SCAN_BLOCK - 1];
}

__global__ __launch_bounds__(256)
void scanB3(ScanJob a, ScanJob b, ScanJob c) {
    const ScanJob& j = (blockIdx.x == 2) ? c : (blockIdx.x == 1) ? b : a;
    __shared__ int s[SCAN_BLOCK];
    int v = ((int)threadIdx.x < j.nbp) ? j.bsums[threadIdx.x] : 0;
    s[threadIdx.x] = v;
    __syncthreads();
    for (int off = 1; off < SCAN_BLOCK; off <<= 1) {
        int t = (threadIdx.x >= off) ? s[threadIdx.x - off] : 0;
        __syncthreads();
        s[threadIdx.x] += t;
        __syncthreads();
    }
    if ((int)threadIdx.x < j.nbp) j.bsums[threadIdx.x] = s[threadIdx.x] - v;
}

__global__ __launch_bounds__(256)
void scanA3(ScanJob a, ScanJob b, ScanJob c) {
    const ScanJob& j = ((int)blockIdx.x >= c.blk0a) ? c :
                       ((int)blockIdx.x >= b.blk0a) ? b : a;
    int idx = (blockIdx.x - j.blk0a) * 256 + threadIdx.x;
    if (idx < j.n) j.rowptr[idx + 1] += j.bsums[idx / SCAN_CHUNK];
    if (idx == 0) j.rowptr[0] = 0;
}

// ======================= prep: cvt x -> bf16, weight frags, biases ===========
// frag layout: cui [fl][m(3)][kt(4)][jt(8)][lane(64)][8],  fl = f*2+l
//              vis [fl][m(2)][kt][jt][lane][8]
// cui m=2 is Wr0+Wr1; vis m=1 is Wr2.

constexpr int FC_CUI = 2 * 2 * 3 * 4 * 8 * 64;
constexpr int FC_VIS = 2 * 2 * 2 * 4 * 8 * 64;

__global__ __launch_bounds__(256)
void prep_all(const float* __restrict__ xc, const float* __restrict__ xv,
              const float* __restrict__ W_l, const float* __restrict__ b_l,
              const float* __restrict__ W_r,
              ushort* __restrict__ xc16, ushort* __restrict__ xv16,
              ushort* __restrict__ Wcui, ushort* __restrict__ Wvis,
              float* __restrict__ Bcui, float* __restrict__ Bvis,
              int RC, int RV) {
    int t = blockIdx.x * 256 + threadIdx.x;
    if (t < RC) {                          // x_cui convert, 8 floats/thread
        int i = t * 8;
        float4 v0 = *(const float4*)(xc + i);
        float4 v1 = *(const float4*)(xc + i + 4);
        u16x8 o = {f2bf(v0.x), f2bf(v0.y), f2bf(v0.z), f2bf(v0.w),
                   f2bf(v1.x), f2bf(v1.y), f2bf(v1.z), f2bf(v1.w)};
        *(u16x8*)(xc16 + i) = o;
        return;
    }
    t -= RC;
    if (t < RV) {                          // x_visit convert
        int i = t * 8;
        float4 v0 = *(const float4*)(xv + i);
        float4 v1 = *(const float4*)(xv + i + 4);
        u16x8 o = {f2bf(v0.x), f2bf(v0.y), f2bf(v0.z), f2bf(v0.w),
                   f2bf(v1.x), f2bf(v1.y), f2bf(v1.z), f2bf(v1.w)};
        *(u16x8*)(xv16 + i) = o;
        return;
    }
    t -= RV;
    if (t < FC_CUI) {
        int lane = t & 63, jt = (t >> 6) & 7, kt = (t >> 9) & 3;
        int q = t >> 11; int m = q % 3, fl = q / 3;
        int j = jt * 16 + (lane & 15);
        int k0 = kt * 32 + (lane >> 4) * 8;
        size_t b0 = (size_t)(fl * 3) * 16384 + (size_t)j * 128 + k0;
        ushort* dst = Wcui + (size_t)t * 8;
        #pragma unroll
        for (int i = 0; i < 8; ++i) {
            float v;
            if (m == 0)      v = W_l[b0 + i];
            else if (m == 1) v = W_l[b0 + 16384 + i];
            else             v = W_r[b0 + i] + W_r[b0 + 16384 + i];
            dst[i] = f2bf(v);
        }
        return;
    }
    t -= FC_CUI;
    if (t < FC_VIS) {
        int lane = t & 63, jt = (t >> 6) & 7, kt = (t >> 9) & 3;
        int q = t >> 11; int m = q & 1, fl = q >> 1;
        int j = jt * 16 + (lane & 15);
        int k0 = kt * 32 + (lane >> 4) * 8;
        size_t b0 = (size_t)(fl * 3 + 2) * 16384 + (size_t)j * 128 + k0;
        ushort* dst = Wvis + (size_t)t * 8;
        #pragma unroll
        for (int i = 0; i < 8; ++i) {
            float v = (m == 0) ? W_l[b0 + i] : W_r[b0 + i];
            dst[i] = f2bf(v);
        }
        return;
    }
    t -= FC_VIS;
    if (t < 512) {
        int j = t & 127, fl = t >> 7;
        Bcui[t] = b_l[fl * 384 + j] + b_l[fl * 384 + 128 + j];
        return;
    }
    t -= 512;
    if (t < 512) {
        int j = t & 127, fl = t >> 7;
        Bvis[t] = b_l[fl * 384 + 256 + j];
    }
}

// ======================= mean aggregation, fused jobs ========================
// 16 lanes per dst row (16B/lane), 16 rows per 256-thread block.
// DUAL=1: src is pair table [row][2][128]; two 16B loads/edge; two outputs.

struct AggJob {
    const ushort* src; const int* rowptr; const int* col;
    ushort* dst; int n; int blk0;
};

template <int DUAL>
__global__ __launch_bounds__(256)
void agg_fused(AggJob j0, AggJob j1, AggJob j2) {
    const AggJob& j = ((int)blockIdx.x >= j2.blk0) ? j2 :
                      ((int)blockIdx.x >= j1.blk0) ? j1 : j0;
    int row = (blockIdx.x - j.blk0) * 16 + (threadIdx.x >> 4);
    if (row >= j.n) return;
    const int coff = (threadIdx.x & 15) * 8;
    const int RS = DUAL ? 256 : 128;
    int beg = j.rowptr[row], end = j.rowptr[row + 1];
    float a0[8] = {0,0,0,0,0,0,0,0};
    float a1[8] = {0,0,0,0,0,0,0,0};
    const ushort* S = j.src + coff;
    int e = beg;
    for (; e + 4 <= end; e += 4) {
        bf16x8 v0[4], v1[4];
        #pragma unroll
        for (int i = 0; i < 4; ++i) {
            const ushort* p = S + (size_t)j.col[e + i] * RS;
            v0[i] = *(const bf16x8*)p;
            if (DUAL) v1[i] = *(const bf16x8*)(p + 128);
        }
        #pragma unroll
        for (int i = 0; i < 4; ++i) {
            acc8(a0, v0[i]);
            if (DUAL) acc8(a1, v1[i]);
        }
    }
    for (; e < end; ++e) {
        const ushort* p = S + (size_t)j.col[e] * RS;
        acc8(a0, *(const bf16x8*)p);
        if (DUAL) acc8(a1, *(const bf16x8*)(p + 128));
    }
    float inv = 1.f / fmaxf((float)(end - beg), 1.f);
    if (DUAL) {
        *(u16x8*)(j.dst + (size_t)row * 256 + coff) = packbf(a0, inv);
        *(u16x8*)(j.dst + (size_t)row * 256 + 128 + coff) = packbf(a1, inv);
    } else {
        *(u16x8*)(j.dst + (size_t)row * 128 + coff) = packbf(a0, inv);
    }
}

// ======================= GEMM, register-resident W, fused jobs ===============
// 512 threads = 8 waves; wave w: filter f=w>>2, cols jt0=(w&3)*2 (2 x 16).
// EPI=0: relu -> bf16 pair buffer [row][f][128]. EPI=1: max over filters -> f32.

struct GemmJob {
    const ushort* X0; const ushort* X1; const ushort* X2;
    int xstr; int foff;
    const ushort* W; int wstr;
    const float* B; int bstr;
    ushort* Yp; float* Yf;
    int n; int M;
};

template <int M, int EPI>
__device__ __forceinline__ void gemm_body(const GemmJob& J, int b, int nb, float* lds) {
    const int lane = threadIdx.x & 63;
    const int w = threadIdx.x >> 6;
    const int f = w >> 2;
    const int jt0 = (w & 3) * 2;
    const int lr = lane & 15, kg = lane >> 4;

    bf16x8 breg[M][4][2];
    const ushort* wf = J.W + (size_t)f * J.wstr;
    #pragma unroll
    for (int m = 0; m < M; ++m)
        #pragma unroll
        for (int kt = 0; kt < 4; ++kt)
            #pragma unroll
            for (int j = 0; j < 2; ++j) {
                int fi = (m * 4 + kt) * 8 + jt0 + j;
                breg[m][kt][j] = *(const bf16x8*)(wf + ((size_t)fi * 64 + lane) * 8);
            }
    const float bb0 = J.B[f * J.bstr + (jt0 + 0) * 16 + lr];
    const float bb1 = J.B[f * J.bstr + (jt0 + 1) * 16 + lr];
    const ushort* Xm[3];
    Xm[0] = J.X0 + f * J.foff;
    Xm[1] = J.X1 + f * J.foff;
    Xm[2] = J.X2 + f * J.foff;
    const int xs = J.xstr;
    const int nt = (J.n + 31) >> 5;
    const bf16x8 zero = {0,0,0,0,0,0,0,0};

    for (int tile = b; tile < nt; tile += nb) {
        const int row0 = tile << 5;
        f32x4 acc[2][2];
        #pragma unroll
        for (int s = 0; s < 2; ++s) {
            acc[s][0] = {bb0, bb0, bb0, bb0};
            acc[s][1] = {bb1, bb1, bb1, bb1};
        }
        #pragma unroll
        for (int m = 0; m < M; ++m) {
            const int ra = row0 + lr, rb = row0 + 16 + lr;
            const ushort* pa = Xm[m] + (size_t)ra * xs + kg * 8;
            const ushort* pb = Xm[m] + (size_t)rb * xs + kg * 8;
            const bool oka = ra < J.n, okb = rb < J.n;
            #pragma unroll
            for (int kt = 0; kt < 4; ++kt) {
                bf16x8 a0 = oka ? *(const bf16x8*)(pa + kt * 32) : zero;
                bf16x8 a1 = okb ? *(const bf16x8*)(pb + kt * 32) : zero;
                acc[0][0] = __builtin_amdgcn_mfma_f32_16x16x32_bf16(a0, breg[m][kt][0], acc[0][0], 0, 0, 0);
                acc[0][1] = __builtin_amdgcn_mfma_f32_16x16x32_bf16(a0, breg[m][kt][1], acc[0][1], 0, 0, 0);
                acc[1][0] = __builtin_amdgcn_mfma_f32_16x16x32_bf16(a1, breg[m][kt][0], acc[1][0], 0, 0, 0);
                acc[1][1] = __builtin_amdgcn_mfma_f32_16x16x32_bf16(a1, breg[m][kt][1], acc[1][1], 0, 0, 0);
            }
        }
        if (EPI == 0) {
            #pragma unroll
            for (int s = 0; s < 2; ++s)
                #pragma unroll
                for (int r = 0; r < 4; ++r) {
                    int row = row0 + s * 16 + kg * 4 + r;
                    if (row >= J.n) continue;
                    #pragma unroll
                    for (int j = 0; j < 2; ++j)
                        J.Yp[(size_t)row * 256 + f * 128 + (jt0 + j) * 16 + lr] =
                            f2bf(fmaxf(acc[s][j][r], 0.f));
                }
        } else {
            if (f == 1) {
                #pragma unroll
                for (int s = 0; s < 2; ++s)
                    #pragma unroll
                    for (int r = 0; r < 4; ++r)
                        #pragma unroll
                        for (int j = 0; j < 2; ++j)
                            lds[(s * 16 + kg * 4 + r) * 128 + (jt0 + j) * 16 + lr] = acc[s][j][r];
            }
            __syncthreads();
            if (f == 0) {
                #pragma unroll
                for (int s = 0; s < 2; ++s)
                    #pragma unroll
                    for (int r = 0; r < 4; ++r) {
                        int rt = s * 16 + kg * 4 + r;
                        int row = row0 + rt;
                        if (row >= J.n) continue;
                        #pragma unroll
                        for (int j = 0; j < 2; ++j) {
                            int c = (jt0 + j) * 16 + lr;
                            J.Yf[(size_t)row * D_ + c] = fmaxf(acc[s][j][r], lds[rt * 128 + c]);
                        }
                    }
            }
            __syncthreads();
        }
    }
}

template <int EPI>
__global__ __launch_bounds__(512)
void gemm_fused(GemmJob jc, GemmJob jv, int splitB) {
    __shared__ float lds[32 * 128];
    const bool isC = (int)blockIdx.x < splitB;
    const GemmJob& J = isC ? jc : jv;
    const int b  = isC ? blockIdx.x : blockIdx.x - splitB;
    const int nb = isC ? splitB : gridDim.x - splitB;
    if (J.M == 3) gemm_body<3, EPI>(J, b, nb, lds);
    else          gemm_body<2, EPI>(J, b, nb, lds);
}

// ---------------------------------------------------------------------------

extern "C" void kernel_launch(void* const* d_in, const int* in_sizes, int n_in,
                              void* d_out, int out_size, void* d_ws, size_t ws_size,
                              hipStream_t stream) {
    const float* x_cui = (const float*)d_in[0];
    const float* x_vis = (const float*)d_in[1];
    const float* W_l   = (const float*)d_in[2];
    const float* b_l   = (const float*)d_in[3];
    const float* W_r   = (const float*)d_in[4];
    const int*   ei_cc = (const int*)d_in[5];
    const int*   ei_vc = (const int*)d_in[6];
    const int*   ei_cv = (const int*)d_in[7];

    const int NC  = in_sizes[0] / D_;
    const int NV  = in_sizes[1] / D_;
    const int ECC = in_sizes[5] / 2;
    const int EVC = in_sizes[6] / 2;
    const int ECV = in_sizes[7] / 2;

    // ---- workspace bump allocator (region reuse keeps peak ~222 MB) ----
    char* ws = (char*)d_ws;
    size_t off = 0;
    auto alloc = [&](size_t bytes) -> char* {
        char* p = ws + off;
        off += (bytes + 511) & ~(size_t)511;
        return p;
    };
    int* rp_cc  = (int*)alloc((size_t)(NC + 1) * 4);
    int* rp_vc  = (int*)alloc((size_t)(NC + 1) * 4);
    int* rp_cv  = (int*)alloc((size_t)(NV + 1) * 4);
    int* col_cc = (int*)alloc((size_t)ECC * 4);
    int* col_vc = (int*)alloc((size_t)EVC * 4);
    int* col_cv = (int*)alloc((size_t)ECV * 4);
    int* cnt    = (int*)alloc((size_t)(2 * NC + NV) * 4);
    int* bsums  = (int*)alloc(3 * 256 * 4);
    ushort* Wcui_lin = (ushort*)alloc((size_t)FC_CUI * 8 * 2);
    ushort* Wvis_lin = (ushort*)alloc((size_t)FC_VIS * 8 * 2);
    float*  Bcui = (float*)alloc(512 * 4);
    float*  Bvis = (float*)alloc(512 * 4);
    ushort* region1 = (ushort*)alloc((size_t)NC * 256 * 2); // aggA|aggB -> pairCC
    ushort* region2 = (ushort*)alloc((size_t)NC * 256 * 2); // xc16|xv16 -> pairVC
    ushort* region3 = (ushort*)alloc((size_t)NV * 256 * 2); // aggV      -> pairCV
    ushort* h1c = (ushort*)alloc((size_t)NC * 256 * 2);     // layer-1 out, pair
    ushort* h1v = (ushort*)alloc((size_t)NV * 256 * 2);
    (void)ws_size;

    ushort* aggA = region1;
    ushort* aggB = region1 + (size_t)NC * 128;
    ushort* xc16 = region2;
    ushort* xv16 = region2 + (size_t)NC * 128;
    ushort* aggV = region3;
    ushort* pairCC = region1;
    ushort* pairVC = region2;
    ushort* pairCV = region3;

    // ---- prep: converts + weight fragments + biases (one dispatch) ----
    const int RC = NC * 16, RV = NV * 16;
    const int prepTot = RC + RV + FC_CUI + FC_VIS + 1024;
    prep_all<<<(prepTot + 255) / 256, 256, 0, stream>>>(
        x_cui, x_vis, W_l, b_l, W_r, xc16, xv16, Wcui_lin, Wvis_lin, Bcui, Bvis, RC, RV);

    // ---- CSR build, fused across 3 edge types ----
    int* cntA = cnt;          // cc (NC)
    int* cntB = cnt + NC;     // vc (NC)
    int* cntC = cnt + 2 * NC; // cv (NV)
    hipMemsetAsync(cnt, 0, (size_t)(2 * NC + NV) * 4, stream);

    EdgeJob eA = {ei_cc, ei_cc + ECC, rp_cc, cntA, col_cc, ECC, 0};
    EdgeJob eB = {ei_vc, ei_vc + EVC, rp_vc, cntB, col_vc, EVC, 0};
    EdgeJob eC = {ei_cv, ei_cv + ECV, rp_cv, cntC, col_cv, ECV, 0};
    int nbA = (ECC + 255) / 256, nbB = (EVC + 255) / 256, nbC = (ECV + 255) / 256;
    eB.blk0 = nbA; eC.blk0 = nbA + nbB;
    count3<<<nbA + nbB + nbC, 256, 0, stream>>>(eA, eB, eC);

    ScanJob sA = {cntA, rp_cc, bsums,       NC, (NC + SCAN_CHUNK - 1) / SCAN_CHUNK, 0, 0};
    ScanJob sB = {cntB, rp_vc, bsums + 256, NC, (NC + SCAN_CHUNK - 1) / SCAN_CHUNK, 0, 0};
    ScanJob sC = {cntC, rp_cv, bsums + 512, NV, (NV + SCAN_CHUNK - 1) / SCAN_CHUNK, 0, 0};
    sB.blk0p = sA.nbp; sC.blk0p = sA.nbp + sB.nbp;
    int aA = (NC + 255) / 256, aB = (NC + 255) / 256, aC = (NV + 255) / 256;
    sB.blk0a = aA; sC.blk0a = aA + aB;
    scanP3<<<sA.nbp + sB.nbp + sC.nbp, 256, 0, stream>>>(sA, sB, sC);
    scanB3<<<3, 256, 0, stream>>>(sA, sB, sC);
    scanA3<<<aA + aB + aC, 256, 0, stream>>>(sA, sB, sC);

    hipMemsetAsync(cnt, 0, (size_t)(2 * NC + NV) * 4, stream);
    fill3<<<nbA + nbB + nbC, 256, 0, stream>>>(eA, eB, eC);

    float* out_cui = (float*)d_out;
    float* out_vis = (float*)d_out + (size_t)NC * D_;

    // ---- layer 1: fused aggregations (single-table), then fused GEMMs ----
    int gA = (NC + 15) / 16, gB = (NC + 15) / 16, gC = (NV + 15) / 16;
    {
        AggJob a0 = {xc16, rp_cc, col_cc, aggA, NC, 0};
        AggJob a1 = {xv16, rp_vc, col_vc, aggB, NC, gA};
        AggJob a2 = {xc16, rp_cv, col_cv, aggV, NV, gA + gB};
        agg_fused<0><<<gA + gB + gC, 256, 0, stream>>>(a0, a1, a2);
    }

    const int tC = (NC + 31) / 32, tV = (NV + 31) / 32;
    const int GG = 512;
    int splitB = (int)((long long)GG * tC / (tC + tV));
    if (splitB < 1) splitB = 1;
    if (splitB > GG - 1) splitB = GG - 1;

    {
        GemmJob jc = {aggA, aggB, xc16, 128, 0,
                      Wcui_lin + 0 * 3 * 16384, 2 * 3 * 16384, Bcui + 0 * 128, 256,
                      h1c, nullptr, NC, 3};
        GemmJob jv = {aggV, xv16, aggV, 128, 0,
                      Wvis_lin + 0 * 2 * 16384, 2 * 2 * 16384, Bvis + 0 * 128, 256,
                      h1v, nullptr, NV, 2};
        gemm_fused<0><<<GG, 512, 0, stream>>>(jc, jv, splitB);
    }

    // ---- layer 2: fused dual aggregations (pair tables), fused max GEMMs ----
    {
        AggJob a0 = {h1c, rp_cc, col_cc, pairCC, NC, 0};
        AggJob a1 = {h1v, rp_vc, col_vc, pairVC, NC, gA};
        AggJob a2 = {h1c, rp_cv, col_cv, pairCV, NV, gA + gB};
        agg_fused<1><<<gA + gB + gC, 256, 0, stream>>>(a0, a1, a2);
    }
    {
        GemmJob jc = {pairCC, pairVC, h1c, 256, 128,
                      Wcui_lin + 1 * 3 * 16384, 2 * 3 * 16384, Bcui + 1 * 128, 256,
                      nullptr, out_cui, NC, 3};
        GemmJob jv = {pairCV, h1v, pairCV, 256, 128,
                      Wvis_lin + 1 * 2 * 16384, 2 * 2 * 16384, Bvis + 1 * 128, 256,
                      nullptr, out_vis, NV, 2};
        gemm_fused<1><<<GG, 512, 0, stream>>>(jc, jv, splitB);
    }
}